// Round 2
// baseline (135.031 us; speedup 1.0000x reference)
//
#include <hip/hip_runtime.h>

#define IN_DIM 128
#define OUT_DIM 32
#define DEG 16
#define EPS 1e-8f

typedef __attribute__((ext_vector_type(8))) short bf16x8;
typedef __attribute__((ext_vector_type(4))) float f32x4;

// ds_swizzle xor-mask patterns (BitMode: (xor<<10)|0x1F), 32-lane domain
#define SWZ(x, p) __int_as_float(__builtin_amdgcn_ds_swizzle(__float_as_int(x), (p)))

static __device__ __forceinline__ unsigned short f2bf(float x) {  // RNE f32->bf16
  unsigned u = __float_as_uint(x);
  u += 0x7FFFu + ((u >> 16) & 1u);
  return (unsigned short)(u >> 16);
}
static __device__ __forceinline__ float bflo(unsigned u) { return __uint_as_float(u << 16); }
static __device__ __forceinline__ float bfhi(unsigned u) { return __uint_as_float(u & 0xFFFF0000u); }

static __device__ __forceinline__ bf16x8 pack8(float4 a, float4 b) {
  bf16x8 r;
  r[0] = (short)f2bf(a.x); r[1] = (short)f2bf(a.y);
  r[2] = (short)f2bf(a.z); r[3] = (short)f2bf(a.w);
  r[4] = (short)f2bf(b.x); r[5] = (short)f2bf(b.y);
  r[6] = (short)f2bf(b.z); r[7] = (short)f2bf(b.w);
  return r;
}

static __device__ __forceinline__ void unp8(uint4 u, float* p) {
  p[0] = bflo(u.x); p[1] = bfhi(u.x); p[2] = bflo(u.y); p[3] = bfhi(u.y);
  p[4] = bflo(u.z); p[5] = bfhi(u.z); p[6] = bflo(u.w); p[7] = bfhi(u.w);
}

// Kernel 1 (UNCHANGED — bit-identical z/nrm keeps the absmax anchor):
// zh = normalize(h @ W^T) rows (bf16), nrm = true f32 row norms.
// One wave = 16 nodes x all 32 outs; h rows read exactly once; norm
// reduction is a 4-swizzle butterfly. ~80% of its 8.1 us HBM floor.
__global__ __launch_bounds__(256) void gemm_norm_kernel(
    const float* __restrict__ h, const float* __restrict__ W,
    unsigned short* __restrict__ zhb, float* __restrict__ nrm, int N) {
  const int tid = threadIdx.x;
  const int wv = tid >> 6;
  const int l = tid & 63;
  const int n16 = l & 15;  // A row (node) / B col (out) lane index
  const int q = l >> 4;    // quad
  const int mb = (blockIdx.x * 4 + wv) * 16;  // 16 nodes per wave
  if (mb >= N) return;     // wave-uniform exit (tail waves)

  // B fragments, both output halves (W = 16 KB, L1/L2-hot)
  bf16x8 bfr[2][4];
#pragma unroll
  for (int oh = 0; oh < 2; ++oh) {
    const float* wr = W + (size_t)(oh * 16 + n16) * IN_DIM + q * 8;
#pragma unroll
    for (int c = 0; c < 4; ++c)
      bfr[oh][c] = pack8(*(const float4*)(wr + c * 32),
                         *(const float4*)(wr + c * 32 + 4));
  }
  // A fragments (16 h rows, read once)
  int m = mb + n16;
  if (m >= N) m = N - 1;  // clamped read; stores guarded
  bf16x8 afr[4];
  {
    const float* hr = h + (size_t)m * IN_DIM + q * 8;
#pragma unroll
    for (int c = 0; c < 4; ++c)
      afr[c] = pack8(*(const float4*)(hr + c * 32),
                     *(const float4*)(hr + c * 32 + 4));
  }

  f32x4 acc0 = {0.f, 0.f, 0.f, 0.f}, acc1 = {0.f, 0.f, 0.f, 0.f};
#pragma unroll
  for (int c = 0; c < 4; ++c) {
    acc0 = __builtin_amdgcn_mfma_f32_16x16x32_bf16(afr[c], bfr[0][c], acc0, 0, 0, 0);
    acc1 = __builtin_amdgcn_mfma_f32_16x16x32_bf16(afr[c], bfr[1][c], acc1, 0, 0, 0);
  }
  // C/D: col(out) = n16 (+16 for acc1), row(node) = q*4 + r

#pragma unroll
  for (int r = 0; r < 4; ++r) {
    float s = acc0[r] * acc0[r] + acc1[r] * acc1[r];
    s += SWZ(s, 0x041F);
    s += SWZ(s, 0x081F);
    s += SWZ(s, 0x101F);
    s += SWZ(s, 0x201F);  // sum over the 16 n16-lanes, all lanes hold it
    const float ns = sqrtf(s);
    const float inv = 1.0f / fmaxf(ns, EPS);
    const float z0 = acc0[r] * inv, z1 = acc1[r] * inv;
    const float p0 = SWZ(z0, 0x041F), p1 = SWZ(z1, 0x041F);  // col n16^1
    const int node = mb + q * 4 + r;
    if (((n16 & 1) == 0) && node < N) {
      unsigned short* zr = zhb + (size_t)node * OUT_DIM;
      *(unsigned*)(zr + n16) =
          (unsigned)f2bf(z0) | ((unsigned)f2bf(p0) << 16);
      *(unsigned*)(zr + 16 + n16) =
          (unsigned)f2bf(z1) | ((unsigned)f2bf(p1) << 16);
    }
    if (n16 == 0 && node < N) nrm[node] = ns;
  }
}

// Kernel 2 (THIS ROUND'S CHANGE — DS-issue cut): 4 nodes per wave, lane =
// one whole edge (e = l&15, nd = l>>4). Round-0's pipeline null showed k2
// is not latency-bound; model says the per-CU DS pipe is (26 issues/iter
// ~176 cyc -> ~14 us). This layout:
//   - dot fully lane-local: 32 fma, ZERO dot swizzles (was 1/edge-pair)
//   - denom: 4 swizzles over the 16-lane edge group (xor 1,2,4,8 stay
//     within the group; nd bit 4 untouched)
//   - LDS reduce reads float2 (b64): lane covers 2 comps x 16 edges ->
//     per-node read issues halved
//   - per-edge DS issues 0.81 -> 0.44 (-46%); iterations 50k -> 25k
// Cost: 36 KB LDS -> 4 blocks/CU = 16 waves/CU (acceptable: issue-bound).
// src load: lane l reads src[base*16 + l] -> 64 consecutive ints, perfectly
// coalesced. Output: float2 per lane, 128 B/node contiguous.
__global__ __launch_bounds__(256) void edge_kernel(
    const unsigned short* __restrict__ zhb, const float* __restrict__ nrm,
    const int* __restrict__ src, const float* __restrict__ beta_p,
    float* __restrict__ out, int N) {
  // 16 node-slots x 16 edges x stride-36 floats = 36 KB.
  // stride 36: b128 writes 16B-aligned (36*4B % 16 == 0), banks uniform
  // 8-deep (= 1KB data floor); b64 reads cover all 32 banks per group.
  __shared__ float xp[16 * DEG * 36];

  const int tid = threadIdx.x;
  const int l = tid & 63, wv = tid >> 6;
  const int e = l & 15;   // edge within node
  const int nd = l >> 4;  // node within wave (0..3)
  const int base = (blockIdx.x * 4 + wv) * 4;  // first node of this wave
  if (base >= N) return;  // wave-uniform exit
  const int n = base + nd;
  const int ne = (n < N) ? n : N - 1;  // clamp loads; stores guarded

  const float beta = *beta_p;
  const int se = src[(size_t)base * DEG + l];  // == src[ne*DEG + e]; coalesced
  const float nrm_s = nrm[se];                 // random 4B gather (L2-hot)

  // full 64B src row + full 64B dst row per lane (dst shared by 16 lanes
  // of the group -> 1 line per node on the TA side)
  const uint4* zs4 = (const uint4*)(zhb + (size_t)se * OUT_DIM);
  const uint4 s0 = zs4[0], s1 = zs4[1], s2 = zs4[2], s3 = zs4[3];
  const uint4* zd4 = (const uint4*)(zhb + (size_t)ne * OUT_DIM);
  const uint4 d0 = zd4[0], d1 = zd4[1], d2 = zd4[2], d3 = zd4[3];

  float vs[32], vd[32];
  unp8(s0, vs + 0); unp8(s1, vs + 8); unp8(s2, vs + 16); unp8(s3, vs + 24);
  unp8(d0, vd + 0); unp8(d1, vd + 8); unp8(d2, vd + 16); unp8(d3, vd + 24);

  // cos = zs_hat . zd_hat, two independent fma chains for ILP
  float pa = vs[0] * vd[0], pb = vs[16] * vd[16];
#pragma unroll
  for (int i = 1; i < 16; ++i) {
    pa = fmaf(vs[i], vd[i], pa);
    pb = fmaf(vs[16 + i], vd[16 + i], pb);
  }
  const float pr = pa + pb;

  const float ex = __expf(beta * (pr - 1.0f));  // beta*(cos-1) <= 0: no max pass

  // segment-softmax denom: sum over the 16 edge-lanes of this node group
  float den = ex;
  den += SWZ(den, 0x041F);
  den += SWZ(den, 0x081F);
  den += SWZ(den, 0x101F);
  den += SWZ(den, 0x201F);  // group-uniform across the 16 lanes
  const float rd = 1.0f / den;

  const float sc = ex * nrm_s;  // weight x un-normalization of zhat_s

  // edge->out transpose via private per-node LDS slot (same-wave RAW,
  // in-order DS per wave -> no barrier)
  float* slot = xp + (wv * 4 + nd) * (DEG * 36) + e * 36;
  float4* wp = (float4*)slot;
#pragma unroll
  for (int q8 = 0; q8 < 8; ++q8)
    wp[q8] = make_float4(sc * vs[4 * q8 + 0], sc * vs[4 * q8 + 1],
                         sc * vs[4 * q8 + 2], sc * vs[4 * q8 + 3]);

  // reduce over 16 edges; lane covers components (2e, 2e+1) of node nd
  const float* rbase = xp + (wv * 4 + nd) * (DEG * 36) + 2 * e;
  float ax = 0.f, ay = 0.f;
#pragma unroll
  for (int e2 = 0; e2 < DEG; ++e2) {
    const float2 v = *(const float2*)(rbase + e2 * 36);
    ax += v.x;
    ay += v.y;
  }

  if (n < N) {  // coalesced: 16 lanes x 8B = 128B contiguous per node
    *(float2*)(out + (size_t)n * OUT_DIM + 2 * e) = make_float2(ax * rd, ay * rd);
  }
}

extern "C" void kernel_launch(void* const* d_in, const int* in_sizes, int n_in,
                              void* d_out, int out_size, void* d_ws, size_t ws_size,
                              hipStream_t stream) {
  const float* h    = (const float*)d_in[0];
  const float* W    = (const float*)d_in[1];
  const float* beta = (const float*)d_in[2];
  const int*   src  = (const int*)d_in[3];
  // d_in[4] = dst == arange(E)//DEG -> node n owns edges [n*DEG, (n+1)*DEG)

  const int N = in_sizes[0] / IN_DIM;

  unsigned short* zhb = (unsigned short*)d_ws;       // N*32 bf16 = 6.4 MB (normalized)
  float* nrm = (float*)(zhb + (size_t)N * OUT_DIM);  // N floats (true norms)

  const int bl1 = (N + 63) / 64;  // 64 nodes per block (4 waves x 16 nodes)
  gemm_norm_kernel<<<bl1, 256, 0, stream>>>(h, W, zhb, nrm, N);

  const int bl2 = (N + 15) / 16;  // 16 nodes per block (4 waves x 4 nodes)
  edge_kernel<<<bl2, 256, 0, stream>>>(zhb, nrm, src, beta, (float*)d_out, N);
}